// Round 5
// baseline (798.589 us; speedup 1.0000x reference)
//
#include <hip/hip_runtime.h>
#include <cstdint>

// ---------------------------------------------------------------------------
// TimeDistributedLSTM: B=32,T=128,S=32,E=256,H=256.  N = B*T = 4096 sequences.
// gates[n,t] = x[n,t]@W_ih^T + h(t-1)@W_hh^T + b  -> cell -> h.
//
// R4 = R3 resubmitted verbatim (R3 bench was a GPUAcquisitionTimeout; no data).
// R3: split the step GEMM. The x-part has no recurrence -> precompute
//   xg = x@W_ih^T for all 32 steps in ONE pass with W_ih RESIDENT IN REGS
//   (read once from L2, not 128 blocks x 32 steps). Recurrent kernel then has
//   K=256 (W_hh only): L2 weight stream 4GB -> 2GB, MFMA/step halved, and
//   freed VGPRs fund explicit prefetch (W dbuf + cross-step xg/Bf0 prefetch).
//   xg (256 MB fp16, fragment layout) lives in d_ws; if ws_size is too small
//   we fall back to the R2 single-kernel path (ws_size is launch-invariant,
//   so the branch is identical every call -> graph-capture safe).
// ---------------------------------------------------------------------------

typedef _Float16 half8 __attribute__((ext_vector_type(8)));
typedef float f32x4 __attribute__((ext_vector_type(4)));

#define LOG2E 1.44269504088896f

#if __has_builtin(__builtin_amdgcn_exp2f)
__device__ __forceinline__ float fexp2(float x) { return __builtin_amdgcn_exp2f(x); }
#else
__device__ __forceinline__ float fexp2(float x) { return exp2f(x); }
#endif
#if __has_builtin(__builtin_amdgcn_rcpf)
__device__ __forceinline__ float frcp(float x) { return __builtin_amdgcn_rcpf(x); }
#else
__device__ __forceinline__ float frcp(float x) { return 1.0f / x; }
#endif

__device__ __forceinline__ float sigf(float z) {
    return frcp(1.0f + fexp2(-LOG2E * z));
}
__device__ __forceinline__ float tanhf_(float z) {
    return 1.0f - 2.0f * frcp(1.0f + fexp2(2.0f * LOG2E * z));
}

// ===========================================================================
// Main path (needs ws >= 1MB + 256MB)
// ===========================================================================

// Pack W_ih -> Wg and W_hh -> Wr as MFMA B-fragments.
// Record r = ((rw*8 + kt)*4 + g)*64 + lane, each 8 halves:
//   col = g*256 + rw*16 + (lane&15),  k = kt*32 + (lane>>4)*8 + jj,
//   value = W[col*256 + k + jj].   (rw: 16 col-groups of 16, kt: 8 k-tiles)
__global__ void prep_w2(const float* __restrict__ Wih, const float* __restrict__ Whh,
                        _Float16* __restrict__ Wg, _Float16* __restrict__ Wr)
{
    int idx  = blockIdx.x * 256 + threadIdx.x;   // 0..65535
    int sel  = idx >> 15;                        // 0: Wg(W_ih), 1: Wr(W_hh)
    int r    = idx & 32767;
    int lane = r & 63;
    int g    = (r >> 6) & 3;
    int kt   = (r >> 8) & 7;
    int rw   = r >> 11;                          // 0..15
    int col  = g * 256 + rw * 16 + (lane & 15);
    int k    = kt * 32 + (lane >> 4) * 8;
    const float* src = (sel ? Whh : Wih) + col * 256 + k;
    half8 hv;
#pragma unroll
    for (int jj = 0; jj < 8; ++jj) hv[jj] = (_Float16)src[jj];
    _Float16* dst = sel ? Wr : Wg;
    *reinterpret_cast<half8*>(dst + (size_t)r * 8) = hv;
}

// xg GEMM: xg[n, t, col] = sum_e x[n,t,e] * W_ih[col][e], fp16, fragment layout.
// Grid 256 = 128 n-groups x 2 col-halves; 512 thr = 8 waves; wave rw=ch*8+w
// owns h-cols [rw*16, rw*16+16). W_ih slice (128 VGPRs) resident across all t.
// xg layout (halves): ((((t*128+ng)*16+rw)*4+q)*64 + lane)*8, q=0..3 packs
// frag (rt=q>>1, g=(q&1)*2+(u>>2), r=u&3).
__global__ __launch_bounds__(512, 1) void xg_gemm(
    const float* __restrict__ x, const _Float16* __restrict__ Wg,
    _Float16* __restrict__ xg)
{
    __shared__ _Float16 Xs[1024 * 8];   // 16 KB: [32 koct][32 row][8]
    const int tid = threadIdx.x;
    const int l   = tid & 63;
    const int w   = tid >> 6;           // 0..7
    const int ng  = blockIdx.x >> 1;
    const int ch  = blockIdx.x & 1;
    const int rw  = ch * 8 + w;
    const int lr  = l & 15;
    const int lk  = l >> 4;

    // resident W_ih fragments: 8 kt x 4 gates x half8 = 128 VGPRs
    half8 Wres[8][4];
#pragma unroll
    for (int kt = 0; kt < 8; ++kt)
#pragma unroll
        for (int g = 0; g < 4; ++g)
            Wres[kt][g] = *reinterpret_cast<const half8*>(
                Wg + ((size_t)(rw * 8 + kt) * 4 + g) * 512 + l * 8);

    // x register staging: thread owns records q0=tid, q1=tid+512
    // record q: row=q>>5, koct=q&31 -> x[((ng*32+row)*32 + t)*256 + koct*8 ..+16)
    const int row0 = tid >> 5,          koct0 = tid & 31;
    const int row1 = (tid + 512) >> 5,  koct1 = (tid + 512) & 31;
    const float* xb0 = x + ((size_t)(ng * 32 + row0) * 32) * 256 + koct0 * 8;
    const float* xb1 = x + ((size_t)(ng * 32 + row1) * 32) * 256 + koct1 * 8;

    float4 xr0a = reinterpret_cast<const float4*>(xb0)[0];
    float4 xr0b = reinterpret_cast<const float4*>(xb0)[1];
    float4 xr1a = reinterpret_cast<const float4*>(xb1)[0];
    float4 xr1b = reinterpret_cast<const float4*>(xb1)[1];

    const int slot0 = koct0 * 32 + (row0 ^ (koct0 & 7));
    const int slot1 = koct1 * 32 + (row1 ^ (koct1 & 7));

    for (int t = 0; t < 32; ++t) {
        // write staged regs -> LDS (fp16, swizzled)
        {
            half8 hv;
            hv[0] = (_Float16)xr0a.x; hv[1] = (_Float16)xr0a.y;
            hv[2] = (_Float16)xr0a.z; hv[3] = (_Float16)xr0a.w;
            hv[4] = (_Float16)xr0b.x; hv[5] = (_Float16)xr0b.y;
            hv[6] = (_Float16)xr0b.z; hv[7] = (_Float16)xr0b.w;
            *reinterpret_cast<half8*>(&Xs[slot0 * 8]) = hv;
            half8 hw;
            hw[0] = (_Float16)xr1a.x; hw[1] = (_Float16)xr1a.y;
            hw[2] = (_Float16)xr1a.z; hw[3] = (_Float16)xr1a.w;
            hw[4] = (_Float16)xr1b.x; hw[5] = (_Float16)xr1b.y;
            hw[6] = (_Float16)xr1b.z; hw[7] = (_Float16)xr1b.w;
            *reinterpret_cast<half8*>(&Xs[slot1 * 8]) = hw;
        }
        // issue loads for t+1 (clamped; latency spans k-loop + store)
        {
            int tn = (t < 31) ? t + 1 : 31;
            xr0a = reinterpret_cast<const float4*>(xb0 + (size_t)tn * 256)[0];
            xr0b = reinterpret_cast<const float4*>(xb0 + (size_t)tn * 256)[1];
            xr1a = reinterpret_cast<const float4*>(xb1 + (size_t)tn * 256)[0];
            xr1b = reinterpret_cast<const float4*>(xb1 + (size_t)tn * 256)[1];
        }
        __syncthreads();

        f32x4 acc[2][4];
#pragma unroll
        for (int rt = 0; rt < 2; ++rt)
#pragma unroll
            for (int g = 0; g < 4; ++g) acc[rt][g] = (f32x4){0.f, 0.f, 0.f, 0.f};

#pragma unroll
        for (int kt = 0; kt < 8; ++kt) {
            half8 a[2];
#pragma unroll
            for (int rt = 0; rt < 2; ++rt) {
                int koct = kt * 4 + lk;
                int row  = rt * 16 + lr;
                int slot = koct * 32 + (row ^ (koct & 7));
                a[rt] = *reinterpret_cast<const half8*>(&Xs[slot * 8]);
            }
#pragma unroll
            for (int g = 0; g < 4; ++g)
#pragma unroll
                for (int rt = 0; rt < 2; ++rt)
                    acc[rt][g] = __builtin_amdgcn_mfma_f32_16x16x32_f16(
                        a[rt], Wres[kt][g], acc[rt][g], 0, 0, 0);
        }
        __syncthreads();   // LDS reads done before next t's staging writes

        // store xg fragments (coalesced: 64 lanes x 16B contiguous per q)
        size_t obase = (((size_t)t * 128 + ng) * 16 + rw) * 4 * 512 + l * 8;
#pragma unroll
        for (int q = 0; q < 4; ++q) {
            int rt = q >> 1, gp = (q & 1) * 2;
            half8 hv;
#pragma unroll
            for (int u = 0; u < 8; ++u)
                hv[u] = (_Float16)acc[rt][gp + (u >> 2)][u & 3];
            *reinterpret_cast<half8*>(xg + obase + (size_t)q * 512) = hv;
        }
    }
}

// Recurrent kernel: 128 blocks x 32 rows, 1024 thr = 16 waves, wave rw owns
// h-cols [rw*16, rw*16+16). K=256 (h only). acc init = xg[t] + bias.
// h double-buffered in LDS (2 x 16KB, swizzled). Cross-step prefetch of
// xg[t+1] and Bf0(kt=0); W register double-buffer inside the k-loop.
__global__ __launch_bounds__(1024, 1) void lstm_rec(
    const _Float16* __restrict__ Wr, const _Float16* __restrict__ xg,
    const float* __restrict__ bih, const float* __restrict__ bhh,
    float* __restrict__ out)
{
    __shared__ _Float16 Hs[2 * 1024 * 8];   // 32 KB
    const int tid = threadIdx.x;
    const int l   = tid & 63;
    const int rw  = tid >> 6;    // 0..15
    const int lr  = l & 15;
    const int lk  = l >> 4;
    const int blk = blockIdx.x;
    const int r0  = blk * 32;

    float bias[4];
#pragma unroll
    for (int g = 0; g < 4; ++g) {
        int col = g * 256 + rw * 16 + lr;
        bias[g] = bih[col] + bhh[col];
    }

    const _Float16* wbase = Wr + (size_t)rw * 16384 + l * 8;  // + kt*2048 + g*512
    const size_t xgb = ((size_t)blk * 16 + rw) * 4 * 512 + l * 8;
    const size_t XT  = (size_t)128 * 16 * 4 * 512;            // t-stride in halves

    // prologue: xg[0]
    half8 xq[4];
#pragma unroll
    for (int q = 0; q < 4; ++q)
        xq[q] = *reinterpret_cast<const half8*>(xg + xgb + (size_t)q * 512);

    half8 Bf0[4], Bf1[4];
    float cst[2][4];
#pragma unroll
    for (int rt = 0; rt < 2; ++rt)
#pragma unroll
        for (int r = 0; r < 4; ++r) cst[rt][r] = 0.f;

    for (int t = 0; t < 32; ++t) {
        // acc init from xg + bias
        f32x4 acc[2][4];
#pragma unroll
        for (int q = 0; q < 4; ++q) {
            int rt = q >> 1, gp = (q & 1) * 2;
#pragma unroll
            for (int u = 0; u < 8; ++u) {
                int g = gp + (u >> 2);
                acc[rt][g][u & 3] = (float)xq[q][u] + bias[g];
            }
        }
        // prefetch xg[t+1] (clamped); latency spans k-loop + cell + barrier
        {
            int tn = (t < 31) ? t + 1 : 31;
#pragma unroll
            for (int q = 0; q < 4; ++q)
                xq[q] = *reinterpret_cast<const half8*>(
                    xg + xgb + (size_t)tn * XT + (size_t)q * 512);
        }

        if (t > 0) {
            const int cb = t & 1;   // h(t-1) buffer
#pragma unroll
            for (int kt = 0; kt < 8; ++kt) {
                if (kt < 7) {   // issue next-kt W into the other buffer
                    if (kt & 1) {
#pragma unroll
                        for (int g = 0; g < 4; ++g)
                            Bf0[g] = *reinterpret_cast<const half8*>(
                                wbase + (kt + 1) * 2048 + g * 512);
                    } else {
#pragma unroll
                        for (int g = 0; g < 4; ++g)
                            Bf1[g] = *reinterpret_cast<const half8*>(
                                wbase + (kt + 1) * 2048 + g * 512);
                    }
                }
                half8 a[2];
#pragma unroll
                for (int rt = 0; rt < 2; ++rt) {
                    int koct = kt * 4 + lk;
                    int row  = rt * 16 + lr;
                    int slot = cb * 1024 + koct * 32 + (row ^ (koct & 7));
                    a[rt] = *reinterpret_cast<const half8*>(&Hs[slot * 8]);
                }
#pragma unroll
                for (int g = 0; g < 4; ++g)
#pragma unroll
                    for (int rt = 0; rt < 2; ++rt)
                        acc[rt][g] = __builtin_amdgcn_mfma_f32_16x16x32_f16(
                            a[rt], (kt & 1) ? Bf1[g] : Bf0[g], acc[rt][g], 0, 0, 0);
            }
        }

        // prefetch next step's first W k-tile (same addresses every step)
        if (t < 31) {
#pragma unroll
            for (int g = 0; g < 4; ++g)
                Bf0[g] = *reinterpret_cast<const half8*>(wbase + g * 512);
        }

        // cell update (lane-local)
        const int nb = (t + 1) & 1;
#pragma unroll
        for (int rt = 0; rt < 2; ++rt)
#pragma unroll
            for (int r = 0; r < 4; ++r) {
                float zi = acc[rt][0][r];
                float zf = acc[rt][1][r];
                float zg = acc[rt][2][r];
                float zo = acc[rt][3][r];
                float ig = sigf(zi);
                float fg = sigf(zf);
                float gg = tanhf_(zg);
                float og = sigf(zo);
                float cn = fg * cst[rt][r] + ig * gg;
                cst[rt][r] = cn;
                float hv = og * tanhf_(cn);
                int m  = rt * 16 + lk * 4 + r;
                int hc = rw * 16 + lr;
                if (t == 31) {
                    out[(size_t)(r0 + m) * 256 + hc] = hv;
                } else {
                    int koct = hc >> 3;
                    int slot = nb * 1024 + koct * 32 + (m ^ (koct & 7));
                    Hs[slot * 8 + (hc & 7)] = (_Float16)hv;
                }
            }
        __syncthreads();
    }
}

// ===========================================================================
// Fallback path (R2, passing @395us): used when ws_size < 257 MB.
// ===========================================================================
__global__ void prep_wf(const float* __restrict__ Wih, const float* __restrict__ Whh,
                        _Float16* __restrict__ Wf)
{
    int idx  = blockIdx.x * 256 + threadIdx.x;
    int lane = idx & 63;
    int g    = (idx >> 6) & 3;
    int kt   = (idx >> 8) & 15;
    int w    = idx >> 12;
    int col  = g * 256 + w * 16 + (lane & 15);
    int kb   = kt * 32 + (lane >> 4) * 8;
    const float* src = (kb < 256) ? (Wih + col * 256 + kb)
                                  : (Whh + col * 256 + (kb - 256));
    half8 hv;
#pragma unroll
    for (int jj = 0; jj < 8; ++jj) hv[jj] = (_Float16)src[jj];
    *reinterpret_cast<half8*>(Wf + (size_t)idx * 8) = hv;
}

__global__ __launch_bounds__(1024, 1) void lstm_fused(
    const float* __restrict__ x, const _Float16* __restrict__ Wf,
    const float* __restrict__ bih, const float* __restrict__ bhh,
    float* __restrict__ out)
{
    __shared__ _Float16 Abuf[2 * 2048 * 8];
    const int tid = threadIdx.x;
    const int l   = tid & 63;
    const int w   = tid >> 6;
    const int lr  = l & 15;
    const int lk  = l >> 4;
    const int r0  = blockIdx.x * 32;

    float bias[4];
#pragma unroll
    for (int g = 0; g < 4; ++g) {
        int col = g * 256 + w * 16 + lr;
        bias[g] = bih[col] + bhh[col];
    }
    {
        int p = tid;
        int row = p >> 5, koct = p & 31;
        const float* xp = x + (((size_t)(r0 + row) * 32 + 0) * 256 + koct * 8);
        float4 v0 = reinterpret_cast<const float4*>(xp)[0];
        float4 v1 = reinterpret_cast<const float4*>(xp)[1];
        half8 hv;
        hv[0] = (_Float16)v0.x; hv[1] = (_Float16)v0.y;
        hv[2] = (_Float16)v0.z; hv[3] = (_Float16)v0.w;
        hv[4] = (_Float16)v1.x; hv[5] = (_Float16)v1.y;
        hv[6] = (_Float16)v1.z; hv[7] = (_Float16)v1.w;
        int slot = koct * 32 + (row ^ (koct & 7));
        *reinterpret_cast<half8*>(&Abuf[slot * 8]) = hv;
        half8 z;
#pragma unroll
        for (int jj = 0; jj < 8; ++jj) z[jj] = (_Float16)0.f;
        *reinterpret_cast<half8*>(&Abuf[(1024 + p) * 8]) = z;
    }
    __syncthreads();

    const _Float16* wbase = Wf + (size_t)w * 32768 + (size_t)l * 8;
    float cst[2][4];
#pragma unroll
    for (int rt = 0; rt < 2; ++rt)
#pragma unroll
        for (int r = 0; r < 4; ++r) cst[rt][r] = 0.f;

    for (int t = 0; t < 32; ++t) {
        const int cb = t & 1;
        const int nb = cb ^ 1;
        f32x4 acc[2][4];
#pragma unroll
        for (int rt = 0; rt < 2; ++rt)
#pragma unroll
            for (int g = 0; g < 4; ++g)
                acc[rt][g] = (f32x4){bias[g], bias[g], bias[g], bias[g]};

#pragma unroll 4
        for (int kt = 0; kt < 16; ++kt) {
            half8 Bf[4];
#pragma unroll
            for (int g = 0; g < 4; ++g)
                Bf[g] = *reinterpret_cast<const half8*>(wbase + (size_t)(kt * 4 + g) * 512);
            half8 a[2];
#pragma unroll
            for (int rt = 0; rt < 2; ++rt) {
                int koct = kt * 4 + lk;
                int row  = rt * 16 + lr;
                int slot = cb * 2048 + koct * 32 + (row ^ (koct & 7));
                a[rt] = *reinterpret_cast<const half8*>(&Abuf[slot * 8]);
            }
#pragma unroll
            for (int g = 0; g < 4; ++g)
#pragma unroll
                for (int rt = 0; rt < 2; ++rt)
                    acc[rt][g] = __builtin_amdgcn_mfma_f32_16x16x32_f16(
                        a[rt], Bf[g], acc[rt][g], 0, 0, 0);
        }

#pragma unroll
        for (int rt = 0; rt < 2; ++rt)
#pragma unroll
            for (int r = 0; r < 4; ++r) {
                float zi = acc[rt][0][r];
                float zf = acc[rt][1][r];
                float zg = acc[rt][2][r];
                float zo = acc[rt][3][r];
                float ig = sigf(zi);
                float fg = sigf(zf);
                float gg = tanhf_(zg);
                float og = sigf(zo);
                float cn = fg * cst[rt][r] + ig * gg;
                cst[rt][r] = cn;
                float hv = og * tanhf_(cn);
                int m  = rt * 16 + lk * 4 + r;
                int hc = w * 16 + lr;
                if (t == 31) {
                    out[(size_t)(r0 + m) * 256 + hc] = hv;
                } else {
                    int koct = 32 + (hc >> 3);
                    int slot = nb * 2048 + koct * 32 + (m ^ (koct & 7));
                    Abuf[slot * 8 + (hc & 7)] = (_Float16)hv;
                }
            }

        if (t < 31) {
            int p = tid;
            int row = p >> 5, koct = p & 31;
            const float* xp =
                x + (((size_t)(r0 + row) * 32 + (t + 1)) * 256 + koct * 8);
            float4 v0 = reinterpret_cast<const float4*>(xp)[0];
            float4 v1 = reinterpret_cast<const float4*>(xp)[1];
            half8 hv;
            hv[0] = (_Float16)v0.x; hv[1] = (_Float16)v0.y;
            hv[2] = (_Float16)v0.z; hv[3] = (_Float16)v0.w;
            hv[4] = (_Float16)v1.x; hv[5] = (_Float16)v1.y;
            hv[6] = (_Float16)v1.z; hv[7] = (_Float16)v1.w;
            int slot = nb * 2048 + koct * 32 + (row ^ (koct & 7));
            *reinterpret_cast<half8*>(&Abuf[slot * 8]) = hv;
        }
        __syncthreads();
    }
}

// ===========================================================================
extern "C" void kernel_launch(void* const* d_in, const int* in_sizes, int n_in,
                              void* d_out, int out_size, void* d_ws, size_t ws_size,
                              hipStream_t stream)
{
    const float* x   = (const float*)d_in[0];   // [32,128,32,256]
    const float* Wih = (const float*)d_in[1];   // [1024,256]
    const float* Whh = (const float*)d_in[2];   // [1024,256]
    const float* bih = (const float*)d_in[3];   // [1024]
    const float* bhh = (const float*)d_in[4];   // [1024]
    float* out = (float*)d_out;                 // [32,128,256]

    const size_t NEED = 1048576ull + 268435456ull;  // Wg+Wr (1MB) + xg (256MB)
    if (ws_size >= NEED) {
        _Float16* Wg  = (_Float16*)d_ws;                          // 512 KB
        _Float16* Wrr = (_Float16*)((char*)d_ws + 524288);        // 512 KB
        _Float16* xgp = (_Float16*)((char*)d_ws + 1048576);       // 256 MB
        prep_w2<<<dim3(256), dim3(256), 0, stream>>>(Wih, Whh, Wg, Wrr);
        xg_gemm<<<dim3(256), dim3(512), 0, stream>>>(x, Wg, xgp);
        lstm_rec<<<dim3(128), dim3(1024), 0, stream>>>(Wrr, xgp, bih, bhh, out);
    } else {
        _Float16* Wf = (_Float16*)d_ws;                           // 1 MB
        prep_wf<<<dim3(256), dim3(256), 0, stream>>>(Wih, Whh, Wf);
        lstm_fused<<<dim3(128), dim3(1024), 0, stream>>>(x, Wf, bih, bhh, out);
    }
}

// Round 6
// 550.394 us; speedup vs baseline: 1.4509x; 1.4509x over previous
//
#include <hip/hip_runtime.h>
#include <cstdint>

// ---------------------------------------------------------------------------
// TimeDistributedLSTM: B=32,T=128,S=32,E=256,H=256.  N = B*T = 4096 sequences.
// gates[n,t] = x[n,t]@W_ih^T + h(t-1)@W_hh^T + b  -> cell -> h.
//
// R6: same split algorithm as R3/R5 (xg = x@W_ih^T precomputed once, recurrent
// kernel K=256), re-implemented inside the measured register envelope:
//   - measured rule: launch_bounds 2nd arg = min BLOCKS/CU; with MFMA in use
//     the arch-VGPR share of the per-wave budget is ~half (1024thr/1blk -> ~64
//     arch regs). R5 spilled because Bf0/Bf1 + xq were FORCED live across the
//     k-loop (needed ~95). R6 uses R2's proven spill-free shape (transient Bf,
//     unroll 4) + xq prefetch confined to the cell phase.
//   - xg_gemm: 256 thr/block (1 blk/CU bound -> arch budget >=256) so the
//     128-reg resident W_ih slice + 32-reg x staging fits; 512 blocks.
// ---------------------------------------------------------------------------

typedef _Float16 half8 __attribute__((ext_vector_type(8)));
typedef float f32x4 __attribute__((ext_vector_type(4)));

#define LOG2E 1.44269504088896f

#if __has_builtin(__builtin_amdgcn_exp2f)
__device__ __forceinline__ float fexp2(float x) { return __builtin_amdgcn_exp2f(x); }
#else
__device__ __forceinline__ float fexp2(float x) { return exp2f(x); }
#endif
#if __has_builtin(__builtin_amdgcn_rcpf)
__device__ __forceinline__ float frcp(float x) { return __builtin_amdgcn_rcpf(x); }
#else
__device__ __forceinline__ float frcp(float x) { return 1.0f / x; }
#endif

__device__ __forceinline__ float sigf(float z) {
    return frcp(1.0f + fexp2(-LOG2E * z));
}
__device__ __forceinline__ float tanhf_(float z) {
    return 1.0f - 2.0f * frcp(1.0f + fexp2(2.0f * LOG2E * z));
}

// ===========================================================================
// Main path (needs ws >= 1MB + 256MB)
// ===========================================================================

// Pack W_ih -> Wg and W_hh -> Wr as MFMA B-fragments.
// Record r = ((rw*8 + kt)*4 + g)*64 + lane, each 8 halves:
//   col = g*256 + rw*16 + (lane&15),  k = kt*32 + (lane>>4)*8 + jj,
//   value = W[col*256 + k + jj].
__global__ void prep_w2(const float* __restrict__ Wih, const float* __restrict__ Whh,
                        _Float16* __restrict__ Wg, _Float16* __restrict__ Wr)
{
    int idx  = blockIdx.x * 256 + threadIdx.x;   // 0..65535
    int sel  = idx >> 15;                        // 0: Wg(W_ih), 1: Wr(W_hh)
    int r    = idx & 32767;
    int lane = r & 63;
    int g    = (r >> 6) & 3;
    int kt   = (r >> 8) & 7;
    int rw   = r >> 11;                          // 0..15
    int col  = g * 256 + rw * 16 + (lane & 15);
    int k    = kt * 32 + (lane >> 4) * 8;
    const float* src = (sel ? Whh : Wih) + col * 256 + k;
    half8 hv;
#pragma unroll
    for (int jj = 0; jj < 8; ++jj) hv[jj] = (_Float16)src[jj];
    _Float16* dst = sel ? Wr : Wg;
    *reinterpret_cast<half8*>(dst + (size_t)r * 8) = hv;
}

// xg GEMM: xg[n, t, col] = sum_e x[n,t,e] * W_ih[col][e], fp16, fragment layout
// (identical layout to R5, verified passing). Grid 512 = 128 n-groups x 4
// col-quarters; 256 thr = 4 waves; wave rw = cq*4+w owns h-cols [rw*16,+16).
// W_ih slice (128 VGPRs) register-resident across all 32 t.
// xg layout (halves): ((((t*128+ng)*16+rw)*4+q)*64 + lane)*8, q=0..3 packs
// frag (rt=q>>1, g=(q&1)*2+(u>>2), r=u&3).
__global__ __launch_bounds__(256, 1) void xg_gemm(
    const float* __restrict__ x, const _Float16* __restrict__ Wg,
    _Float16* __restrict__ xg)
{
    __shared__ _Float16 Xs[1024 * 8];   // 16 KB: [32 koct][32 row][8]
    const int tid = threadIdx.x;
    const int l   = tid & 63;
    const int w   = tid >> 6;           // 0..3
    const int ng  = blockIdx.x >> 2;    // 0..127
    const int cq  = blockIdx.x & 3;     // 0..3
    const int rw  = cq * 4 + w;         // 0..15
    const int lr  = l & 15;
    const int lk  = l >> 4;

    // resident W_ih fragments: 8 kt x 4 gates x half8 = 128 VGPRs
    half8 Wres[8][4];
#pragma unroll
    for (int kt = 0; kt < 8; ++kt)
#pragma unroll
        for (int g = 0; g < 4; ++g)
            Wres[kt][g] = *reinterpret_cast<const half8*>(
                Wg + ((size_t)(rw * 8 + kt) * 4 + g) * 512 + l * 8);

    // x register staging: thread owns 4 records p = i*256+tid
    const float* xb[4];
    int slot[4];
    float4 xa[4], xc[4];
#pragma unroll
    for (int i = 0; i < 4; ++i) {
        int p = i * 256 + tid;          // 0..1023
        int row = p >> 5, koct = p & 31;
        xb[i]   = x + ((size_t)(ng * 32 + row) * 32) * 256 + koct * 8;
        slot[i] = koct * 32 + (row ^ (koct & 7));
        xa[i] = reinterpret_cast<const float4*>(xb[i])[0];
        xc[i] = reinterpret_cast<const float4*>(xb[i])[1];
    }

    for (int t = 0; t < 32; ++t) {
        // write staged regs -> LDS (fp16, swizzled)
#pragma unroll
        for (int i = 0; i < 4; ++i) {
            half8 hv;
            hv[0] = (_Float16)xa[i].x; hv[1] = (_Float16)xa[i].y;
            hv[2] = (_Float16)xa[i].z; hv[3] = (_Float16)xa[i].w;
            hv[4] = (_Float16)xc[i].x; hv[5] = (_Float16)xc[i].y;
            hv[6] = (_Float16)xc[i].z; hv[7] = (_Float16)xc[i].w;
            *reinterpret_cast<half8*>(&Xs[slot[i] * 8]) = hv;
        }
        // issue loads for t+1 (clamped); latency spans k-loop
        {
            int tn = (t < 31) ? t + 1 : 31;
#pragma unroll
            for (int i = 0; i < 4; ++i) {
                xa[i] = reinterpret_cast<const float4*>(xb[i] + (size_t)tn * 256)[0];
                xc[i] = reinterpret_cast<const float4*>(xb[i] + (size_t)tn * 256)[1];
            }
        }
        __syncthreads();

        f32x4 acc[2][4];
#pragma unroll
        for (int rt = 0; rt < 2; ++rt)
#pragma unroll
            for (int g = 0; g < 4; ++g) acc[rt][g] = (f32x4){0.f, 0.f, 0.f, 0.f};

#pragma unroll
        for (int kt = 0; kt < 8; ++kt) {
            half8 a[2];
#pragma unroll
            for (int rt = 0; rt < 2; ++rt) {
                int koct = kt * 4 + lk;
                int row  = rt * 16 + lr;
                int sl   = koct * 32 + (row ^ (koct & 7));
                a[rt] = *reinterpret_cast<const half8*>(&Xs[sl * 8]);
            }
#pragma unroll
            for (int g = 0; g < 4; ++g)
#pragma unroll
                for (int rt = 0; rt < 2; ++rt)
                    acc[rt][g] = __builtin_amdgcn_mfma_f32_16x16x32_f16(
                        a[rt], Wres[kt][g], acc[rt][g], 0, 0, 0);
        }
        __syncthreads();   // LDS reads done before next t's staging writes

        // store xg fragments (coalesced: 64 lanes x 16B contiguous per q)
        size_t obase = (((size_t)t * 128 + ng) * 16 + rw) * 4 * 512 + (size_t)l * 8;
#pragma unroll
        for (int q = 0; q < 4; ++q) {
            int rt = q >> 1, gp = (q & 1) * 2;
            half8 hv;
#pragma unroll
            for (int u = 0; u < 8; ++u)
                hv[u] = (_Float16)acc[rt][gp + (u >> 2)][u & 3];
            *reinterpret_cast<half8*>(xg + obase + (size_t)q * 512) = hv;
        }
    }
}

// Recurrent kernel: 128 blocks x 32 rows, 1024 thr = 16 waves, wave rw owns
// h-cols [rw*16,+16). K=256 (W_hh only). acc init = xg[t] + bias.
// R2's proven spill-free k-loop shape: transient Bf[4], #pragma unroll 4.
// xq prefetch for t+1 issued in the CELL phase only (not live across k-loop).
// Single 16 KB Hs buffer (read in k-loop, barrier, rewritten by cell).
__global__ __launch_bounds__(1024, 1) void lstm_rec(
    const _Float16* __restrict__ Wr, const _Float16* __restrict__ xg,
    const float* __restrict__ bih, const float* __restrict__ bhh,
    float* __restrict__ out)
{
    __shared__ _Float16 Hs[1024 * 8];   // 16 KB: [32 koct][32 row][8]
    const int tid = threadIdx.x;
    const int l   = tid & 63;
    const int rw  = tid >> 6;    // 0..15
    const int lr  = l & 15;
    const int lk  = l >> 4;
    const int blk = blockIdx.x;
    const int r0  = blk * 32;

    float bias[4];
#pragma unroll
    for (int g = 0; g < 4; ++g) {
        int col = g * 256 + rw * 16 + lr;
        bias[g] = bih[col] + bhh[col];
    }

    const _Float16* wbase  = Wr + (size_t)rw * 16384 + (size_t)l * 8;
    const _Float16* xgbase = xg + ((size_t)blk * 16 + rw) * 4 * 512 + (size_t)l * 8;
    const size_t XT = (size_t)128 * 16 * 4 * 512;   // t-stride in halves

    // prologue: xg[0]
    half8 xq[4];
#pragma unroll
    for (int q = 0; q < 4; ++q)
        xq[q] = *reinterpret_cast<const half8*>(xgbase + (size_t)q * 512);

    float cst[2][4];
#pragma unroll
    for (int rt = 0; rt < 2; ++rt)
#pragma unroll
        for (int r = 0; r < 4; ++r) cst[rt][r] = 0.f;

    for (int t = 0; t < 32; ++t) {
        // acc init from xg + bias (consumes xq -> regs free for the k-loop)
        f32x4 acc[2][4];
#pragma unroll
        for (int q = 0; q < 4; ++q) {
            int rt = q >> 1, gp = (q & 1) * 2;
#pragma unroll
            for (int u = 0; u < 8; ++u) {
                int g = gp + (u >> 2);
                acc[rt][g][u & 3] = (float)xq[q][u] + bias[g];
            }
        }

        if (t > 0) {
            // k-loop: 8 k-tiles of 32; transient Bf, unroll 4 (R2 shape)
#pragma unroll 4
            for (int kt = 0; kt < 8; ++kt) {
                half8 Bf[4];
#pragma unroll
                for (int g = 0; g < 4; ++g)
                    Bf[g] = *reinterpret_cast<const half8*>(
                        wbase + (size_t)(kt * 4 + g) * 512);
                half8 a[2];
#pragma unroll
                for (int rt = 0; rt < 2; ++rt) {
                    int koct = kt * 4 + lk;
                    int row  = rt * 16 + lr;
                    int sl   = koct * 32 + (row ^ (koct & 7));
                    a[rt] = *reinterpret_cast<const half8*>(&Hs[sl * 8]);
                }
#pragma unroll
                for (int g = 0; g < 4; ++g)
#pragma unroll
                    for (int rt = 0; rt < 2; ++rt)
                        acc[rt][g] = __builtin_amdgcn_mfma_f32_16x16x32_f16(
                            a[rt], Bf[g], acc[rt][g], 0, 0, 0);
            }
        }
        __syncthreads();   // all Hs reads complete before cell rewrites Hs

        // prefetch xg[t+1]: live only across cell + barrier (not the k-loop)
        if (t < 31) {
#pragma unroll
            for (int q = 0; q < 4; ++q)
                xq[q] = *reinterpret_cast<const half8*>(
                    xgbase + (size_t)(t + 1) * XT + (size_t)q * 512);
        }

        // cell update (lane-local: i/f/g/o frags share (row,col) per lane)
#pragma unroll
        for (int rt = 0; rt < 2; ++rt)
#pragma unroll
            for (int r = 0; r < 4; ++r) {
                float zi = acc[rt][0][r];
                float zf = acc[rt][1][r];
                float zg = acc[rt][2][r];
                float zo = acc[rt][3][r];
                float ig = sigf(zi);
                float fg = sigf(zf);
                float gg = tanhf_(zg);
                float og = sigf(zo);
                float cn = fg * cst[rt][r] + ig * gg;
                cst[rt][r] = cn;
                float hv = og * tanhf_(cn);
                int m  = rt * 16 + lk * 4 + r;
                int hc = rw * 16 + lr;
                if (t == 31) {
                    out[(size_t)(r0 + m) * 256 + hc] = hv;
                } else {
                    int koct = hc >> 3;
                    int sl   = koct * 32 + (m ^ (koct & 7));
                    Hs[sl * 8 + (hc & 7)] = (_Float16)hv;
                }
            }
        __syncthreads();   // h(t) visible for next step's k-loop
    }
}

// ===========================================================================
// Fallback path (R2, passing @395us): used when ws_size < 257 MB.
// ===========================================================================
__global__ void prep_wf(const float* __restrict__ Wih, const float* __restrict__ Whh,
                        _Float16* __restrict__ Wf)
{
    int idx  = blockIdx.x * 256 + threadIdx.x;
    int lane = idx & 63;
    int g    = (idx >> 6) & 3;
    int kt   = (idx >> 8) & 15;
    int w    = idx >> 12;
    int col  = g * 256 + w * 16 + (lane & 15);
    int kb   = kt * 32 + (lane >> 4) * 8;
    const float* src = (kb < 256) ? (Wih + col * 256 + kb)
                                  : (Whh + col * 256 + (kb - 256));
    half8 hv;
#pragma unroll
    for (int jj = 0; jj < 8; ++jj) hv[jj] = (_Float16)src[jj];
    *reinterpret_cast<half8*>(Wf + (size_t)idx * 8) = hv;
}

__global__ __launch_bounds__(1024, 1) void lstm_fused(
    const float* __restrict__ x, const _Float16* __restrict__ Wf,
    const float* __restrict__ bih, const float* __restrict__ bhh,
    float* __restrict__ out)
{
    __shared__ _Float16 Abuf[2 * 2048 * 8];
    const int tid = threadIdx.x;
    const int l   = tid & 63;
    const int w   = tid >> 6;
    const int lr  = l & 15;
    const int lk  = l >> 4;
    const int r0  = blockIdx.x * 32;

    float bias[4];
#pragma unroll
    for (int g = 0; g < 4; ++g) {
        int col = g * 256 + w * 16 + lr;
        bias[g] = bih[col] + bhh[col];
    }
    {
        int p = tid;
        int row = p >> 5, koct = p & 31;
        const float* xp = x + (((size_t)(r0 + row) * 32 + 0) * 256 + koct * 8);
        float4 v0 = reinterpret_cast<const float4*>(xp)[0];
        float4 v1 = reinterpret_cast<const float4*>(xp)[1];
        half8 hv;
        hv[0] = (_Float16)v0.x; hv[1] = (_Float16)v0.y;
        hv[2] = (_Float16)v0.z; hv[3] = (_Float16)v0.w;
        hv[4] = (_Float16)v1.x; hv[5] = (_Float16)v1.y;
        hv[6] = (_Float16)v1.z; hv[7] = (_Float16)v1.w;
        int slot = koct * 32 + (row ^ (koct & 7));
        *reinterpret_cast<half8*>(&Abuf[slot * 8]) = hv;
        half8 z;
#pragma unroll
        for (int jj = 0; jj < 8; ++jj) z[jj] = (_Float16)0.f;
        *reinterpret_cast<half8*>(&Abuf[(1024 + p) * 8]) = z;
    }
    __syncthreads();

    const _Float16* wbase = Wf + (size_t)w * 32768 + (size_t)l * 8;
    float cst[2][4];
#pragma unroll
    for (int rt = 0; rt < 2; ++rt)
#pragma unroll
        for (int r = 0; r < 4; ++r) cst[rt][r] = 0.f;

    for (int t = 0; t < 32; ++t) {
        const int cb = t & 1;
        const int nb = cb ^ 1;
        f32x4 acc[2][4];
#pragma unroll
        for (int rt = 0; rt < 2; ++rt)
#pragma unroll
            for (int g = 0; g < 4; ++g)
                acc[rt][g] = (f32x4){bias[g], bias[g], bias[g], bias[g]};

#pragma unroll 4
        for (int kt = 0; kt < 16; ++kt) {
            half8 Bf[4];
#pragma unroll
            for (int g = 0; g < 4; ++g)
                Bf[g] = *reinterpret_cast<const half8*>(wbase + (size_t)(kt * 4 + g) * 512);
            half8 a[2];
#pragma unroll
            for (int rt = 0; rt < 2; ++rt) {
                int koct = kt * 4 + lk;
                int row  = rt * 16 + lr;
                int slot = cb * 2048 + koct * 32 + (row ^ (koct & 7));
                a[rt] = *reinterpret_cast<const half8*>(&Abuf[slot * 8]);
            }
#pragma unroll
            for (int g = 0; g < 4; ++g)
#pragma unroll
                for (int rt = 0; rt < 2; ++rt)
                    acc[rt][g] = __builtin_amdgcn_mfma_f32_16x16x32_f16(
                        a[rt], Bf[g], acc[rt][g], 0, 0, 0);
        }

#pragma unroll
        for (int rt = 0; rt < 2; ++rt)
#pragma unroll
            for (int r = 0; r < 4; ++r) {
                float zi = acc[rt][0][r];
                float zf = acc[rt][1][r];
                float zg = acc[rt][2][r];
                float zo = acc[rt][3][r];
                float ig = sigf(zi);
                float fg = sigf(zf);
                float gg = tanhf_(zg);
                float og = sigf(zo);
                float cn = fg * cst[rt][r] + ig * gg;
                cst[rt][r] = cn;
                float hv = og * tanhf_(cn);
                int m  = rt * 16 + lk * 4 + r;
                int hc = w * 16 + lr;
                if (t == 31) {
                    out[(size_t)(r0 + m) * 256 + hc] = hv;
                } else {
                    int koct = 32 + (hc >> 3);
                    int slot = nb * 2048 + koct * 32 + (m ^ (koct & 7));
                    Abuf[slot * 8 + (hc & 7)] = (_Float16)hv;
                }
            }

        if (t < 31) {
            int p = tid;
            int row = p >> 5, koct = p & 31;
            const float* xp =
                x + (((size_t)(r0 + row) * 32 + (t + 1)) * 256 + koct * 8);
            float4 v0 = reinterpret_cast<const float4*>(xp)[0];
            float4 v1 = reinterpret_cast<const float4*>(xp)[1];
            half8 hv;
            hv[0] = (_Float16)v0.x; hv[1] = (_Float16)v0.y;
            hv[2] = (_Float16)v0.z; hv[3] = (_Float16)v0.w;
            hv[4] = (_Float16)v1.x; hv[5] = (_Float16)v1.y;
            hv[6] = (_Float16)v1.z; hv[7] = (_Float16)v1.w;
            int slot = nb * 2048 + koct * 32 + (row ^ (koct & 7));
            *reinterpret_cast<half8*>(&Abuf[slot * 8]) = hv;
        }
        __syncthreads();
    }
}

// ===========================================================================
extern "C" void kernel_launch(void* const* d_in, const int* in_sizes, int n_in,
                              void* d_out, int out_size, void* d_ws, size_t ws_size,
                              hipStream_t stream)
{
    const float* x   = (const float*)d_in[0];   // [32,128,32,256]
    const float* Wih = (const float*)d_in[1];   // [1024,256]
    const float* Whh = (const float*)d_in[2];   // [1024,256]
    const float* bih = (const float*)d_in[3];   // [1024]
    const float* bhh = (const float*)d_in[4];   // [1024]
    float* out = (float*)d_out;                 // [32,128,256]

    const size_t NEED = 1048576ull + 268435456ull;  // Wg+Wr (1MB) + xg (256MB)
    if (ws_size >= NEED) {
        _Float16* Wg  = (_Float16*)d_ws;                          // 512 KB
        _Float16* Wrr = (_Float16*)((char*)d_ws + 524288);        // 512 KB
        _Float16* xgp = (_Float16*)((char*)d_ws + 1048576);       // 256 MB
        prep_w2<<<dim3(256), dim3(256), 0, stream>>>(Wih, Whh, Wg, Wrr);
        xg_gemm<<<dim3(512), dim3(256), 0, stream>>>(x, Wg, xgp);
        lstm_rec<<<dim3(128), dim3(1024), 0, stream>>>(Wrr, xgp, bih, bhh, out);
    } else {
        _Float16* Wf = (_Float16*)d_ws;                           // 1 MB
        prep_wf<<<dim3(256), dim3(256), 0, stream>>>(Wih, Whh, Wf);
        lstm_fused<<<dim3(128), dim3(1024), 0, stream>>>(x, Wf, bih, bhh, out);
    }
}